// Round 1
// baseline (5331.793 us; speedup 1.0000x reference)
//
#include <hip/hip_runtime.h>
#include <math.h>

// NTM fused persistent kernel for MI355X.
// Shapes: N=32, T=64, C1=128, C2=256, H=512 (all f32).
// Structure per step t (3 grid barriers):
//   [blocks 0..63]  ATTN(t): online-softmax attention over c_x[:,t]  ||  [blocks 64..255] c-update(t-1)
//   [all blocks]    GRU(t): r-combine -> h_t  (weights LDS-resident, loaded once)
//   [all blocks]    PROJ(t): k,beta (for t+1), e,v (for c-update)
// Grid barrier: monotonic counter in d_ws (memset each launch -> deterministic replay).

#define NBAT 32
#define TSTEPS 64
#define C1D 128
#define C2D 256
#define HD 512

static __device__ __forceinline__ float dot4f(float4 a, float4 b) {
  return a.x * b.x + a.y * b.y + a.z * b.z + a.w * b.w;
}
static __device__ __forceinline__ float sigm(float x) { return 1.0f / (1.0f + __expf(-x)); }

__global__ void __launch_bounds__(256) ntm_fused(
    const float* __restrict__ h0, const float* __restrict__ c0,
    const float* __restrict__ c_x,
    const float* __restrict__ Wk, const float* __restrict__ bk,
    const float* __restrict__ Wb, const float* __restrict__ bb,
    const float* __restrict__ We, const float* __restrict__ be,
    const float* __restrict__ Wv, const float* __restrict__ bv,
    const float* __restrict__ Wih, const float* __restrict__ bih,
    const float* __restrict__ Whh, const float* __restrict__ bhh,
    float* __restrict__ out, float* __restrict__ wsf, unsigned* __restrict__ bar)
{
  const int tid = threadIdx.x;
  const int bid = blockIdx.x;
  const int lane = tid & 63;
  const int wid = tid >> 6;

  // ---- workspace layout (floats) ----
  float* hbufA = wsf;                         // [NBAT*HD]
  float* hbufB = hbufA + NBAT * HD;           // [NBAT*HD]
  float* kbuf  = hbufB + NBAT * HD;           // [NBAT*C2D]
  float* betab = kbuf + NBAT * C2D;           // [NBAT]
  float* rpart = betab + NBAT;                // [2*NBAT*258]  (m,l,racc[256]) per half per n
  float* scoreb = rpart + 2 * NBAT * 258;     // [NBAT*TSTEPS*C1D]
  float* MLb   = scoreb + NBAT * TSTEPS * C1D; // [NBAT*TSTEPS*2] (M, 1/L)
  float* earr  = MLb + NBAT * TSTEPS * 2;     // [NBAT*TSTEPS*C2D]
  float* varr  = earr + NBAT * TSTEPS * C2D;  // [NBAT*TSTEPS*C2D]
  float* hs_out = out;                         // [NBAT*TSTEPS*HD]
  float* cs_out = out + NBAT * TSTEPS * HD;    // [NBAT*TSTEPS*C1D*C2D]

  // ---- LDS ----
  __shared__ float s_r[8448];        // GRU: combined r [32][264]; ATTN: scratch (first 1040)
  __shared__ float s_scale[64];      // per-n (s0/L, s1/L)
  __shared__ float s_wih[6 * 260];   // W_ih rows {jj,g} for this block's j-pair (stride 260)
  __shared__ float s_whh[6 * 516];   // W_hh rows (stride 516)
  __shared__ float s_wev[3 * 516];   // Wk/We/Wv row for c = bid
  __shared__ float s_wb[512];        // Wb row (used by block 0)

  const int j0 = bid * 2;
  for (int idx = tid; idx < 6 * C2D; idx += 256) {
    int row = idx >> 8, c = idx & (C2D - 1);
    int jj = row / 3, g = row % 3;
    s_wih[row * 260 + c] = Wih[(g * HD + j0 + jj) * C2D + c];
  }
  for (int idx = tid; idx < 6 * HD; idx += 256) {
    int row = idx >> 9, c = idx & (HD - 1);
    int jj = row / 3, g = row % 3;
    s_whh[row * 516 + c] = Whh[(g * HD + j0 + jj) * HD + c];
  }
  for (int idx = tid; idx < 3 * HD; idx += 256) {
    int row = idx >> 9, c = idx & (HD - 1);
    const float* __restrict__ src = (row == 0) ? Wk : (row == 1) ? We : Wv;
    s_wev[row * 516 + c] = src[bid * HD + c];
  }
  for (int idx = tid; idx < HD; idx += 256) s_wb[idx] = Wb[idx];

  // ---- c-state registers for update waves (blocks 64..255; wave owns rows cw + 768*j) ----
  float4 cst0 = {}, cst1 = {}, cst2 = {}, cst3 = {}, cst4 = {}, cst5 = {};
  int cw = 0;
  if (bid >= 64) {
    cw = (bid - 64) * 4 + wid;  // 0..767
    cst0 = *(const float4*)(c0 + (size_t)(cw + 0 * 768) * C2D + lane * 4);
    cst1 = *(const float4*)(c0 + (size_t)(cw + 1 * 768) * C2D + lane * 4);
    cst2 = *(const float4*)(c0 + (size_t)(cw + 2 * 768) * C2D + lane * 4);
    cst3 = *(const float4*)(c0 + (size_t)(cw + 3 * 768) * C2D + lane * 4);
    cst4 = *(const float4*)(c0 + (size_t)(cw + 4 * 768) * C2D + lane * 4);
    if (cw < 256) cst5 = *(const float4*)(c0 + (size_t)(cw + 5 * 768) * C2D + lane * 4);
  }
  __syncthreads();

  unsigned gen = 0;
  auto gridbar_f = [&]() {
    ++gen;
    __syncthreads();
    if (tid == 0) {
      __threadfence();
      __hip_atomic_fetch_add(bar, 1u, __ATOMIC_RELAXED, __HIP_MEMORY_SCOPE_AGENT);
      const unsigned target = gen * 256u;
      while (__hip_atomic_load(bar, __ATOMIC_RELAXED, __HIP_MEMORY_SCOPE_AGENT) < target)
        __builtin_amdgcn_s_sleep(1);
      __threadfence();
    }
    __syncthreads();
  };

  // ---- PROJ: k,beta,e,v from hsrc ----
  auto phase_proj = [&](const float* __restrict__ hsrc, int t, bool write_ev) {
    const int n = tid >> 3, s = tid & 7;
    const float* hp = hsrc + n * HD;
    float kp = 0.f, ep = 0.f, vp = 0.f, bp = 0.f;
#pragma unroll
    for (int x = 0; x < 16; ++x) {
      const int cix = s * 64 + ((4 * x + 8 * s) & 63);  // bank-rotated, 16B aligned
      const float4 hv = *(const float4*)(hp + cix);
      kp += dot4f(hv, *(const float4*)(s_wev + cix));
      ep += dot4f(hv, *(const float4*)(s_wev + 516 + cix));
      vp += dot4f(hv, *(const float4*)(s_wev + 1032 + cix));
      if (bid == 0) bp += dot4f(hv, *(const float4*)(s_wb + cix));
    }
#pragma unroll
    for (int m = 1; m < 8; m <<= 1) {
      kp += __shfl_xor(kp, m);
      ep += __shfl_xor(ep, m);
      vp += __shfl_xor(vp, m);
    }
    if (bid == 0) {
#pragma unroll
      for (int m = 1; m < 8; m <<= 1) bp += __shfl_xor(bp, m);
    }
    if (s == 0) {
      kbuf[n * C2D + bid] = kp + bk[bid];
      if (write_ev) {
        earr[(n * TSTEPS + t) * C2D + bid] = sigm(ep + be[bid]);
        varr[(n * TSTEPS + t) * C2D + bid] = vp + bv[bid];
      }
      if (bid == 0) {
        const float xb = bp + bb[0];
        const float bpos = fmaxf(xb, 0.f), bneg = fminf(xb, 0.f);
        betab[n] = log1pf(__expf(bneg)) + bpos + log1pf(__expf(-bpos)) +
                   (1.0f - 0.6931471805599453f);
      }
    }
  };

  // ---- ATTN: online softmax over i for (n = bid>>1, half = bid&1) ----
  auto phase_attn = [&](int t) {
    const int n = bid >> 1, half = bid & 1;
    // kn = ||k||
    const float kc = kbuf[n * C2D + tid];
    float sq = kc * kc;
#pragma unroll
    for (int m = 1; m < 64; m <<= 1) sq += __shfl_xor(sq, m);
    if (lane == 0) s_r[1036 + wid] = sq;
    __syncthreads();
    const float kn = sqrtf(s_r[1036] + s_r[1037] + s_r[1038] + s_r[1039]);
    const float beta = betab[n];
    const float4 kv = *(const float4*)(kbuf + n * C2D + lane * 4);
    const int i_base = half * 64 + wid * 16;
    const float* base = c_x + ((size_t)((n * TSTEPS + t) * C1D + i_base)) * C2D + lane * 4;
    float4 xb[8];  // ring-8 prefetch (HBM latency hiding at 1 wave/SIMD)
#pragma unroll
    for (int r = 0; r < 8; ++r) xb[r] = *(const float4*)(base + r * C2D);
    float m_run = -3.0e38f, l_run = 0.f;
    float r0 = 0.f, r1 = 0.f, r2 = 0.f, r3 = 0.f;
#pragma unroll
    for (int rep = 0; rep < 16; ++rep) {
      const float4 xv = xb[rep & 7];
      if (rep < 8) xb[rep & 7] = *(const float4*)(base + (rep + 8) * C2D);
      float np = dot4f(xv, kv);
      float cp = dot4f(xv, xv);
#pragma unroll
      for (int m = 1; m < 64; m <<= 1) {
        np += __shfl_xor(np, m);
        cp += __shfl_xor(cp, m);
      }
      const float score = beta * np / fmaxf(sqrtf(cp) * kn, 1e-8f);
      if (lane == 0) scoreb[(n * TSTEPS + t) * C1D + i_base + rep] = score;
      const float mn = fmaxf(m_run, score);
      const float corr = __expf(m_run - mn);
      const float p = __expf(score - mn);
      l_run = l_run * corr + p;
      r0 = r0 * corr + p * xv.x;
      r1 = r1 * corr + p * xv.y;
      r2 = r2 * corr + p * xv.z;
      r3 = r3 * corr + p * xv.w;
      m_run = mn;
    }
    *(float4*)(s_r + wid * 256 + lane * 4) = make_float4(r0, r1, r2, r3);
    if (lane == 0) { s_r[1024 + wid] = m_run; s_r[1028 + wid] = l_run; }
    __syncthreads();
    const float mw0 = s_r[1024], mw1 = s_r[1025], mw2 = s_r[1026], mw3 = s_r[1027];
    const float mb = fmaxf(fmaxf(mw0, mw1), fmaxf(mw2, mw3));
    const float e0 = __expf(mw0 - mb), e1 = __expf(mw1 - mb);
    const float e2 = __expf(mw2 - mb), e3 = __expf(mw3 - mb);
    const float lb = s_r[1028] * e0 + s_r[1029] * e1 + s_r[1030] * e2 + s_r[1031] * e3;
    const float racc = s_r[tid] * e0 + s_r[256 + tid] * e1 + s_r[512 + tid] * e2 + s_r[768 + tid] * e3;
    float* rp = rpart + (half * NBAT + n) * 258;
    if (tid == 0) { rp[0] = mb; rp[1] = lb; }
    rp[2 + tid] = racc;
  };

  // ---- c-update for step tc (blocks 64..255; state in registers) ----
  auto c_step = [&](int tc) {
#pragma unroll
    for (int jr = 0; jr < 6; ++jr) {
      const int row = cw + jr * 768;
      if (jr < 5 || row < 4096) {
        const int nn = row >> 7, ii = row & 127;
        const float sc = scoreb[(nn * TSTEPS + tc) * C1D + ii];
        const float M = MLb[(nn * TSTEPS + tc) * 2];
        const float iL = MLb[(nn * TSTEPS + tc) * 2 + 1];
        const float wgt = __expf(sc - M) * iL;
        const float4 e4 = *(const float4*)(earr + (size_t)(nn * TSTEPS + tc) * C2D + lane * 4);
        const float4 v4 = *(const float4*)(varr + (size_t)(nn * TSTEPS + tc) * C2D + lane * 4);
        float4& cc = (jr == 0) ? cst0 : (jr == 1) ? cst1 : (jr == 2) ? cst2
                   : (jr == 3) ? cst3 : (jr == 4) ? cst4 : cst5;
        cc.x = cc.x * (1.f - wgt * e4.x) + wgt * v4.x;
        cc.y = cc.y * (1.f - wgt * e4.y) + wgt * v4.y;
        cc.z = cc.z * (1.f - wgt * e4.z) + wgt * v4.z;
        cc.w = cc.w * (1.f - wgt * e4.w) + wgt * v4.w;
        *(float4*)(cs_out + ((size_t)(nn * TSTEPS + tc) * C1D + ii) * C2D + lane * 4) = cc;
      }
    }
  };

  // ---- GRU: combine r, compute h_t for j-pair (j0, j0+1) across all n ----
  auto phase_gru = [&](const float* __restrict__ hsrc, float* __restrict__ hnext, int t) {
    if (tid < NBAT) {
      const int n = tid;
      const float m0 = rpart[n * 258], l0 = rpart[n * 258 + 1];
      const float m1 = rpart[(NBAT + n) * 258], l1 = rpart[(NBAT + n) * 258 + 1];
      const float M = fmaxf(m0, m1);
      const float x0 = __expf(m0 - M), x1 = __expf(m1 - M);
      const float invL = 1.f / (l0 * x0 + l1 * x1);
      s_scale[2 * n] = x0 * invL;
      s_scale[2 * n + 1] = x1 * invL;
      if (bid == n) {  // blocks 0..31 publish (M, 1/L) for the c-update
        MLb[(n * TSTEPS + t) * 2] = M;
        MLb[(n * TSTEPS + t) * 2 + 1] = invL;
      }
    }
    __syncthreads();
    {
      const int c = tid;
#pragma unroll 4
      for (int n2 = 0; n2 < NBAT; ++n2) {
        const float a = rpart[n2 * 258 + 2 + c];
        const float b2 = rpart[(NBAT + n2) * 258 + 2 + c];
        s_r[n2 * 264 + c] = a * s_scale[2 * n2] + b2 * s_scale[2 * n2 + 1];
      }
    }
    __syncthreads();
    const int n = tid >> 3, s = tid & 7;
    float a00 = 0, a01 = 0, a02i = 0, a02h = 0, a10 = 0, a11 = 0, a12i = 0, a12h = 0;
    const float* rb = s_r + n * 264 + s * 32;
#pragma unroll
    for (int x = 0; x < 8; ++x) {
      const int o = (4 * x + 4 * s) & 31;
      const float4 rv = *(const float4*)(rb + o);
      const int cix = s * 32 + o;
      a00 += dot4f(rv, *(const float4*)(s_wih + cix));
      a01 += dot4f(rv, *(const float4*)(s_wih + 260 + cix));
      a02i += dot4f(rv, *(const float4*)(s_wih + 520 + cix));
      a10 += dot4f(rv, *(const float4*)(s_wih + 780 + cix));
      a11 += dot4f(rv, *(const float4*)(s_wih + 1040 + cix));
      a12i += dot4f(rv, *(const float4*)(s_wih + 1300 + cix));
    }
    const float* hb = hsrc + n * HD + s * 64;
#pragma unroll
    for (int x = 0; x < 16; ++x) {
      const int o = (4 * x + 8 * s) & 63;
      const float4 hv = *(const float4*)(hb + o);
      const int cix = s * 64 + o;
      a00 += dot4f(hv, *(const float4*)(s_whh + cix));
      a01 += dot4f(hv, *(const float4*)(s_whh + 516 + cix));
      a02h += dot4f(hv, *(const float4*)(s_whh + 1032 + cix));
      a10 += dot4f(hv, *(const float4*)(s_whh + 1548 + cix));
      a11 += dot4f(hv, *(const float4*)(s_whh + 2064 + cix));
      a12h += dot4f(hv, *(const float4*)(s_whh + 2580 + cix));
    }
#pragma unroll
    for (int m = 1; m < 8; m <<= 1) {
      a00 += __shfl_xor(a00, m);
      a01 += __shfl_xor(a01, m);
      a02i += __shfl_xor(a02i, m);
      a02h += __shfl_xor(a02h, m);
      a10 += __shfl_xor(a10, m);
      a11 += __shfl_xor(a11, m);
      a12i += __shfl_xor(a12i, m);
      a12h += __shfl_xor(a12h, m);
    }
    if (s == 0) {
      {
        const int j = j0;
        const float rg = sigm(a00 + bih[j] + bhh[j]);
        const float z = sigm(a01 + bih[HD + j] + bhh[HD + j]);
        const float ng = tanhf(a02i + bih[2 * HD + j] + rg * (a02h + bhh[2 * HD + j]));
        const float hp = hsrc[n * HD + j];
        const float hn = (1.f - z) * ng + z * hp;
        hnext[n * HD + j] = hn;
        hs_out[(n * TSTEPS + t) * HD + j] = hn;
      }
      {
        const int j = j0 + 1;
        const float rg = sigm(a10 + bih[j] + bhh[j]);
        const float z = sigm(a11 + bih[HD + j] + bhh[HD + j]);
        const float ng = tanhf(a12i + bih[2 * HD + j] + rg * (a12h + bhh[2 * HD + j]));
        const float hp = hsrc[n * HD + j];
        const float hn = (1.f - z) * ng + z * hp;
        hnext[n * HD + j] = hn;
        hs_out[(n * TSTEPS + t) * HD + j] = hn;
      }
    }
  };

  // ================= main sequence =================
  phase_proj(h0, 0, false);  // k_0, beta_0 from h0
  gridbar_f();
  for (int t = 0; t < TSTEPS; ++t) {
    if (bid < 64) {
      phase_attn(t);
    } else if (t > 0) {
      c_step(t - 1);  // overlapped with ATTN
    }
    gridbar_f();
    const float* hsrc = (t == 0) ? h0 : ((t & 1) ? hbufB : hbufA);
    float* hnext = (t & 1) ? hbufA : hbufB;
    phase_gru(hsrc, hnext, t);
    gridbar_f();
    phase_proj(hnext, t, true);
    gridbar_f();
  }
  if (bid >= 64) c_step(TSTEPS - 1);
}

extern "C" void kernel_launch(void* const* d_in, const int* in_sizes, int n_in,
                              void* d_out, int out_size, void* d_ws, size_t ws_size,
                              hipStream_t stream) {
  const float* h0 = (const float*)d_in[0];
  const float* c0 = (const float*)d_in[1];
  const float* c_x = (const float*)d_in[2];
  const float* Wk = (const float*)d_in[3];
  const float* bk = (const float*)d_in[4];
  const float* Wb = (const float*)d_in[5];
  const float* bb = (const float*)d_in[6];
  const float* We = (const float*)d_in[7];
  const float* be = (const float*)d_in[8];
  const float* Wv = (const float*)d_in[9];
  const float* bv = (const float*)d_in[10];
  const float* Wih = (const float*)d_in[11];
  const float* bih = (const float*)d_in[12];
  const float* Whh = (const float*)d_in[13];
  const float* bhh = (const float*)d_in[14];

  unsigned* bar = (unsigned*)d_ws;
  float* wsf = (float*)((char*)d_ws + 256);

  (void)hipMemsetAsync(d_ws, 0, 256, stream);  // reset barrier counter every launch
  ntm_fused<<<dim3(256), dim3(256), 0, stream>>>(h0, c0, c_x, Wk, bk, Wb, bb, We, be,
                                                 Wv, bv, Wih, bih, Whh, bhh,
                                                 (float*)d_out, wsf, bar);
}

// Round 3
// 3374.971 us; speedup vs baseline: 1.5798x; 1.5798x over previous
//
#include <hip/hip_runtime.h>
#include <math.h>

// NTM split into: (1) serial h-chain kernel (128 blocks, 3 cheap grid barriers/step,
// tiny dirty set per fence), (2) massively parallel c-scan kernel (no barriers,
// streams the 268 MB cs output with nontemporal stores).
// Shapes: N=32, T=64, C1=128, C2=256, H=512 (all f32).

#define NBAT 32
#define TSTEPS 64
#define C1D 128
#define C2D 256
#define HD 512
#define NBLK 128  // chain blocks

typedef float f32x4 __attribute__((ext_vector_type(4)));

static __device__ __forceinline__ float dot4f(float4 a, float4 b) {
  return a.x * b.x + a.y * b.y + a.z * b.z + a.w * b.w;
}
static __device__ __forceinline__ float sigm(float x) { return 1.0f / (1.0f + __expf(-x)); }

__global__ void __launch_bounds__(256) ntm_chain(
    const float* __restrict__ h0, const float* __restrict__ c_x,
    const float* __restrict__ Wk, const float* __restrict__ bk,
    const float* __restrict__ Wb, const float* __restrict__ bb,
    const float* __restrict__ We, const float* __restrict__ be,
    const float* __restrict__ Wv, const float* __restrict__ bv,
    const float* __restrict__ Wih, const float* __restrict__ bih,
    const float* __restrict__ Whh, const float* __restrict__ bhh,
    float* __restrict__ hs_out, float* __restrict__ wsf, unsigned* __restrict__ bar)
{
  const int tid = threadIdx.x;
  const int bid = blockIdx.x;
  const int lane = tid & 63;
  const int wid = tid >> 6;

  // ---- workspace layout (floats) ----
  float* hbufA = wsf;                          // [32*512]
  float* hbufB = hbufA + NBAT * HD;            // [32*512]
  float* kbuf  = hbufB + NBAT * HD;            // [32*256]
  float* betab = kbuf + NBAT * C2D;            // [32]
  float* rpart = betab + NBAT;                 // [4*32][258] (m,l,racc[256])
  float* wbuf  = rpart + 4 * NBAT * 258;       // [32][64][128] scores -> w
  float* earr  = wbuf + NBAT * TSTEPS * C1D;   // [32][64][256]
  float* varr  = earr + NBAT * TSTEPS * C2D;   // [32][64][256]

  // ---- LDS (~119 KB, 1 block/CU) ----
  __shared__ float s_tile[32 * C2D];   // c_x tile for (n,q): 32 rows x 1KB
  __shared__ float s_r[NBAT * 264];    // GRU combined r; ATTN scratch [0..1039]
  __shared__ float s_scale[192];       // [n*4+q] scales; [128+n]=M; [160+n]=invL
  __shared__ float s_wih[12 * 260];    // 4 feat x 3 gates, stride 260
  __shared__ float s_whh[12 * 516];
  __shared__ float s_wev[6 * 516];     // 2 ch x (k,e,v)
  __shared__ float s_wb[HD];

  const int n_att = bid >> 2, q_att = bid & 3;
  const int j0 = bid * 4;    // GRU features
  const int c0ch = bid * 2;  // PROJ channels

  for (int idx = tid; idx < 12 * C2D; idx += 256) {
    const int row = idx >> 8, c = idx & (C2D - 1);
    const int f = row / 3, g = row % 3;
    s_wih[row * 260 + c] = Wih[(g * HD + j0 + f) * C2D + c];
  }
  for (int idx = tid; idx < 12 * HD; idx += 256) {
    const int row = idx >> 9, c = idx & (HD - 1);
    const int f = row / 3, g = row % 3;
    s_whh[row * 516 + c] = Whh[(g * HD + j0 + f) * HD + c];
  }
  for (int idx = tid; idx < 6 * HD; idx += 256) {
    const int row = idx >> 9, c = idx & (HD - 1);
    const int ch = row / 3, which = row % 3;
    const float* __restrict__ src = (which == 0) ? Wk : (which == 1) ? We : Wv;
    s_wev[row * 516 + c] = src[(c0ch + ch) * HD + c];
  }
  for (int idx = tid; idx < HD; idx += 256) s_wb[idx] = Wb[idx];
  __syncthreads();

  unsigned gen = 0;
  auto gridbar = [&]() {
    ++gen;
    __syncthreads();
    if (tid == 0) {
      __hip_atomic_fetch_add(bar, 1u, __ATOMIC_RELEASE, __HIP_MEMORY_SCOPE_AGENT);
      const unsigned target = gen * (unsigned)NBLK;
      while (__hip_atomic_load(bar, __ATOMIC_RELAXED, __HIP_MEMORY_SCOPE_AGENT) < target)
        __builtin_amdgcn_s_sleep(2);
      __builtin_amdgcn_fence(__ATOMIC_ACQUIRE, "agent");
    }
    __syncthreads();
  };

  // c_x prefetch: regs (issued early) -> LDS (committed late). 8 float4/thread.
  float4 pf[8];
  auto prefetch_issue = [&](int t) {
    const float* src = c_x + ((size_t)((n_att * TSTEPS + t) * C1D + q_att * 32)) * C2D + lane * 4;
#pragma unroll
    for (int k = 0; k < 8; ++k) pf[k] = *(const float4*)(src + (wid * 8 + k) * C2D);
  };
  auto prefetch_commit = [&]() {
#pragma unroll
    for (int k = 0; k < 8; ++k) *(float4*)(s_tile + (wid * 8 + k) * C2D + lane * 4) = pf[k];
  };

  // ---- PROJ: k (always), e,v (write_ev), beta (bid 0) from hsrc ----
  auto phase_proj = [&](const float* __restrict__ hsrc, int t, bool write_ev) {
    const int n = tid >> 3, s = tid & 7;
    const float* hp = hsrc + n * HD;
    float k0 = 0, e0 = 0, v0 = 0, k1 = 0, e1 = 0, v1 = 0, bp = 0;
#pragma unroll
    for (int x = 0; x < 16; ++x) {
      const int cix = s * 64 + ((4 * x + 8 * s) & 63);
      const float4 hv = *(const float4*)(hp + cix);
      k0 += dot4f(hv, *(const float4*)(s_wev + cix));
      e0 += dot4f(hv, *(const float4*)(s_wev + 516 + cix));
      v0 += dot4f(hv, *(const float4*)(s_wev + 1032 + cix));
      k1 += dot4f(hv, *(const float4*)(s_wev + 1548 + cix));
      e1 += dot4f(hv, *(const float4*)(s_wev + 2064 + cix));
      v1 += dot4f(hv, *(const float4*)(s_wev + 2580 + cix));
      if (bid == 0) bp += dot4f(hv, *(const float4*)(s_wb + cix));
    }
#pragma unroll
    for (int m = 1; m < 8; m <<= 1) {
      k0 += __shfl_xor(k0, m); e0 += __shfl_xor(e0, m); v0 += __shfl_xor(v0, m);
      k1 += __shfl_xor(k1, m); e1 += __shfl_xor(e1, m); v1 += __shfl_xor(v1, m);
    }
    if (bid == 0) {
#pragma unroll
      for (int m = 1; m < 8; m <<= 1) bp += __shfl_xor(bp, m);
    }
    if (s == 0) {
      kbuf[n * C2D + c0ch] = k0 + bk[c0ch];
      kbuf[n * C2D + c0ch + 1] = k1 + bk[c0ch + 1];
      if (write_ev) {
        earr[(n * TSTEPS + t) * C2D + c0ch] = sigm(e0 + be[c0ch]);
        earr[(n * TSTEPS + t) * C2D + c0ch + 1] = sigm(e1 + be[c0ch + 1]);
        varr[(n * TSTEPS + t) * C2D + c0ch] = v0 + bv[c0ch];
        varr[(n * TSTEPS + t) * C2D + c0ch + 1] = v1 + bv[c0ch + 1];
      }
      if (bid == 0) {
        const float xb = bp + bb[0];
        const float bpos = fmaxf(xb, 0.f), bneg = fminf(xb, 0.f);
        betab[n] = log1pf(__expf(bneg)) + bpos + log1pf(__expf(-bpos)) +
                   (1.0f - 0.6931471805599453f);
      }
    }
  };

  // ---- ATTN: online softmax over this block's 32 i-rows, from LDS tile ----
  auto phase_attn = [&](int t) {
    const float kc = kbuf[n_att * C2D + tid];
    float sq = kc * kc;
#pragma unroll
    for (int m = 1; m < 64; m <<= 1) sq += __shfl_xor(sq, m);
    if (lane == 0) s_r[1036 + wid] = sq;
    __syncthreads();
    const float kn = sqrtf(s_r[1036] + s_r[1037] + s_r[1038] + s_r[1039]);
    const float beta = betab[n_att];
    const float4 kv = *(const float4*)(kbuf + n_att * C2D + lane * 4);
    float m_run = -3.0e38f, l_run = 0.f;
    float r0 = 0.f, r1 = 0.f, r2 = 0.f, r3 = 0.f;
    const int rowbase = wid * 8;
#pragma unroll
    for (int k = 0; k < 8; ++k) {
      const float4 xv = *(const float4*)(s_tile + (rowbase + k) * C2D + lane * 4);
      float np = dot4f(xv, kv);
      float cp = dot4f(xv, xv);
#pragma unroll
      for (int m = 1; m < 64; m <<= 1) {
        np += __shfl_xor(np, m);
        cp += __shfl_xor(cp, m);
      }
      const float score = beta * np / fmaxf(sqrtf(cp) * kn, 1e-8f);
      if (lane == 0) wbuf[(n_att * TSTEPS + t) * C1D + q_att * 32 + rowbase + k] = score;
      const float mn = fmaxf(m_run, score);
      const float corr = __expf(m_run - mn);
      const float p = __expf(score - mn);
      l_run = l_run * corr + p;
      r0 = r0 * corr + p * xv.x;
      r1 = r1 * corr + p * xv.y;
      r2 = r2 * corr + p * xv.z;
      r3 = r3 * corr + p * xv.w;
      m_run = mn;
    }
    *(float4*)(s_r + wid * 256 + lane * 4) = make_float4(r0, r1, r2, r3);
    if (lane == 0) { s_r[1024 + wid] = m_run; s_r[1028 + wid] = l_run; }
    __syncthreads();
    const float mw0 = s_r[1024], mw1 = s_r[1025], mw2 = s_r[1026], mw3 = s_r[1027];
    const float mb = fmaxf(fmaxf(mw0, mw1), fmaxf(mw2, mw3));
    const float e0 = __expf(mw0 - mb), e1 = __expf(mw1 - mb);
    const float e2 = __expf(mw2 - mb), e3 = __expf(mw3 - mb);
    const float lb = s_r[1028] * e0 + s_r[1029] * e1 + s_r[1030] * e2 + s_r[1031] * e3;
    const float racc = s_r[tid] * e0 + s_r[256 + tid] * e1 + s_r[512 + tid] * e2 + s_r[768 + tid] * e3;
    float* rp = rpart + (q_att * NBAT + n_att) * 258;
    if (tid == 0) { rp[0] = mb; rp[1] = lb; }
    rp[2 + tid] = racc;
  };

  // ---- GRU: combine r, finalize w row (bid<32), compute 4 h-features x 32 n ----
  auto phase_gru = [&](const float* __restrict__ hsrc, float* __restrict__ hnext, int t) {
    if (tid < NBAT) {
      const int n = tid;
      float mq[4], lq[4];
#pragma unroll
      for (int q = 0; q < 4; ++q) {
        mq[q] = rpart[(q * NBAT + n) * 258];
        lq[q] = rpart[(q * NBAT + n) * 258 + 1];
      }
      const float M = fmaxf(fmaxf(mq[0], mq[1]), fmaxf(mq[2], mq[3]));
      float x[4], L = 0.f;
#pragma unroll
      for (int q = 0; q < 4; ++q) { x[q] = __expf(mq[q] - M); L += lq[q] * x[q]; }
      const float invL = 1.f / L;
#pragma unroll
      for (int q = 0; q < 4; ++q) s_scale[n * 4 + q] = x[q] * invL;
      s_scale[128 + n] = M;
      s_scale[160 + n] = invL;
    }
    __syncthreads();
    {
      const int c = tid;
#pragma unroll 4
      for (int n2 = 0; n2 < NBAT; ++n2) {
        float acc = 0.f;
#pragma unroll
        for (int q = 0; q < 4; ++q)
          acc += rpart[(q * NBAT + n2) * 258 + 2 + c] * s_scale[n2 * 4 + q];
        s_r[n2 * 264 + c] = acc;
      }
    }
    __syncthreads();
    if (bid < NBAT && tid < C1D) {
      const float M = s_scale[128 + bid], invL = s_scale[160 + bid];
      float* wp = wbuf + (bid * TSTEPS + t) * C1D + tid;
      *wp = __expf(*wp - M) * invL;
    }
    const int n = tid >> 3, s = tid & 7;
    float aR[4] = {0, 0, 0, 0}, aZ[4] = {0, 0, 0, 0};
    float aNi[4] = {0, 0, 0, 0}, aNh[4] = {0, 0, 0, 0};
    const float* rb = s_r + n * 264 + s * 32;
#pragma unroll
    for (int x = 0; x < 8; ++x) {
      const int o = (4 * x + 4 * s) & 31;
      const float4 rv = *(const float4*)(rb + o);
      const int cix = s * 32 + o;
#pragma unroll
      for (int f = 0; f < 4; ++f) {
        aR[f]  += dot4f(rv, *(const float4*)(s_wih + (f * 3 + 0) * 260 + cix));
        aZ[f]  += dot4f(rv, *(const float4*)(s_wih + (f * 3 + 1) * 260 + cix));
        aNi[f] += dot4f(rv, *(const float4*)(s_wih + (f * 3 + 2) * 260 + cix));
      }
    }
    const float* hb = hsrc + n * HD + s * 64;
#pragma unroll
    for (int x = 0; x < 16; ++x) {
      const int o = (4 * x + 8 * s) & 63;
      const float4 hv = *(const float4*)(hb + o);
      const int cix = s * 64 + o;
#pragma unroll
      for (int f = 0; f < 4; ++f) {
        aR[f]  += dot4f(hv, *(const float4*)(s_whh + (f * 3 + 0) * 516 + cix));
        aZ[f]  += dot4f(hv, *(const float4*)(s_whh + (f * 3 + 1) * 516 + cix));
        aNh[f] += dot4f(hv, *(const float4*)(s_whh + (f * 3 + 2) * 516 + cix));
      }
    }
#pragma unroll
    for (int m = 1; m < 8; m <<= 1) {
#pragma unroll
      for (int f = 0; f < 4; ++f) {
        aR[f] += __shfl_xor(aR[f], m);
        aZ[f] += __shfl_xor(aZ[f], m);
        aNi[f] += __shfl_xor(aNi[f], m);
        aNh[f] += __shfl_xor(aNh[f], m);
      }
    }
    if (s == 0) {
#pragma unroll
      for (int f = 0; f < 4; ++f) {
        const int j = j0 + f;
        const float rg = sigm(aR[f] + bih[j] + bhh[j]);
        const float z = sigm(aZ[f] + bih[HD + j] + bhh[HD + j]);
        const float ng = tanhf(aNi[f] + bih[2 * HD + j] + rg * (aNh[f] + bhh[2 * HD + j]));
        const float hp = hsrc[n * HD + j];
        const float hn = (1.f - z) * ng + z * hp;
        hnext[n * HD + j] = hn;
        hs_out[(n * TSTEPS + t) * HD + j] = hn;
      }
    }
  };

  // ================= main =================
  prefetch_issue(0);
  phase_proj(h0, 0, false);
  prefetch_commit();
  gridbar();
  for (int t = 0; t < TSTEPS; ++t) {
    phase_attn(t);
    if (t < TSTEPS - 1) prefetch_issue(t + 1);
    gridbar();
    const float* hsrc = (t == 0) ? h0 : ((t & 1) ? hbufB : hbufA);
    float* hnext = (t & 1) ? hbufA : hbufB;
    phase_gru(hsrc, hnext, t);
    gridbar();
    phase_proj(hnext, t, true);
    if (t < TSTEPS - 1) prefetch_commit();
    gridbar();
  }
}

// ---- parallel c-scan: c_t = c_{t-1}*(1 - w_t e_t) + w_t v_t, all t in registers ----
__global__ void __launch_bounds__(256) ntm_cscan(
    const float* __restrict__ c0, const float* __restrict__ wsf,
    float* __restrict__ out)
{
  const float* wbuf = wsf + 2 * NBAT * HD + NBAT * C2D + NBAT + 4 * NBAT * 258;
  const float* earr = wbuf + NBAT * TSTEPS * C1D;
  const float* varr = earr + NBAT * TSTEPS * C2D;
  float* cs_out = out + NBAT * TSTEPS * HD;

  const int tid = threadIdx.x;
  const int lane = tid & 63, wid = tid >> 6;
  const int n = blockIdx.x >> 3, g = blockIdx.x & 7;
  const int i0 = g * 16 + wid * 4;

  f32x4 c[4];
#pragma unroll
  for (int r = 0; r < 4; ++r)
    c[r] = *(const f32x4*)(c0 + ((size_t)(n * C1D + i0 + r)) * C2D + lane * 4);

  const float* ep = earr + (size_t)n * TSTEPS * C2D + lane * 4;
  const float* vp = varr + (size_t)n * TSTEPS * C2D + lane * 4;
  const float* wp = wbuf + (size_t)n * TSTEPS * C1D + i0;

  f32x4 e_nxt = *(const f32x4*)(ep);
  f32x4 v_nxt = *(const f32x4*)(vp);
  for (int t = 0; t < TSTEPS; ++t) {
    const f32x4 e4 = e_nxt, v4 = v_nxt;
    if (t + 1 < TSTEPS) {
      e_nxt = *(const f32x4*)(ep + (t + 1) * C2D);
      v_nxt = *(const f32x4*)(vp + (t + 1) * C2D);
    }
#pragma unroll
    for (int r = 0; r < 4; ++r) {
      const float wr = wp[t * C1D + r];
      c[r] = c[r] * (1.f - wr * e4) + wr * v4;
      __builtin_nontemporal_store(
          c[r], (f32x4*)(cs_out + ((size_t)((n * TSTEPS + t) * C1D + i0 + r)) * C2D + lane * 4));
    }
  }
}

extern "C" void kernel_launch(void* const* d_in, const int* in_sizes, int n_in,
                              void* d_out, int out_size, void* d_ws, size_t ws_size,
                              hipStream_t stream) {
  const float* h0 = (const float*)d_in[0];
  const float* c0 = (const float*)d_in[1];
  const float* c_x = (const float*)d_in[2];
  const float* Wk = (const float*)d_in[3];
  const float* bk = (const float*)d_in[4];
  const float* Wb = (const float*)d_in[5];
  const float* bb = (const float*)d_in[6];
  const float* We = (const float*)d_in[7];
  const float* be = (const float*)d_in[8];
  const float* Wv = (const float*)d_in[9];
  const float* bv = (const float*)d_in[10];
  const float* Wih = (const float*)d_in[11];
  const float* bih = (const float*)d_in[12];
  const float* Whh = (const float*)d_in[13];
  const float* bhh = (const float*)d_in[14];

  unsigned* bar = (unsigned*)d_ws;
  float* wsf = (float*)((char*)d_ws + 256);

  (void)hipMemsetAsync(d_ws, 0, 256, stream);  // reset barrier counter (deterministic replay)
  ntm_chain<<<dim3(NBLK), dim3(256), 0, stream>>>(h0, c_x, Wk, bk, Wb, bb, We, be, Wv, bv,
                                                  Wih, bih, Whh, bhh, (float*)d_out, wsf, bar);
  ntm_cscan<<<dim3(256), dim3(256), 0, stream>>>(c0, wsf, (float*)d_out);
}